// Round 1
// baseline (398.916 us; speedup 1.0000x reference)
//
#include <hip/hip_runtime.h>
#include <hip/hip_bf16.h>
#include <math.h>

#define WAVE 64

// ---------------------------------------------------------------------------
// CSR build: count degrees -> single-block scan -> scatter fill (bucketed by dst)
// ---------------------------------------------------------------------------
__global__ void count_kernel(const int* __restrict__ dst, int* __restrict__ deg, int E) {
    int e = blockIdx.x * blockDim.x + threadIdx.x;
    if (e < E) atomicAdd(&deg[dst[e]], 1);
}

__global__ __launch_bounds__(1024) void scan_kernel(const int* __restrict__ deg,
                                                    int* __restrict__ offs,
                                                    int* __restrict__ cursor, int n) {
    __shared__ int sums[1024];
    const int t = threadIdx.x;
    const int CH = (n + 1023) / 1024;
    int lo = t * CH;
    int hi = lo + CH; if (hi > n) hi = n;
    int s = 0;
    for (int i = lo; i < hi; ++i) s += deg[i];
    sums[t] = s;
    __syncthreads();
    // Hillis-Steele inclusive scan over 1024 partial sums
    for (int off = 1; off < 1024; off <<= 1) {
        int val = (t >= off) ? sums[t - off] : 0;
        __syncthreads();
        sums[t] += val;
        __syncthreads();
    }
    int base = (t == 0) ? 0 : sums[t - 1];
    for (int i = lo; i < hi; ++i) {
        offs[i] = base;
        cursor[i] = base;
        base += deg[i];
    }
    if (t == 1023) offs[n] = sums[1023];
}

__global__ void fill_kernel(const int* __restrict__ src, const int* __restrict__ dst,
                            int* __restrict__ cursor, int* __restrict__ csrc, int E) {
    int e = blockIdx.x * blockDim.x + threadIdx.x;
    if (e < E) {
        int p = atomicAdd(&cursor[dst[e]], 1);
        csrc[p] = src[e];
    }
}

// ---------------------------------------------------------------------------
// Linear: out[n,C] = relu?(in[n,K] @ W[K,C] + b). W staged in LDS.
// 256 threads; each thread owns 4 consecutive output cols (float4 tile).
// ---------------------------------------------------------------------------
template <int K, int C, bool RELU>
__global__ __launch_bounds__(256) void lin_kernel(const float* __restrict__ in,
                                                  const float* __restrict__ W,
                                                  const float* __restrict__ bias,
                                                  float* __restrict__ out, int n) {
    __shared__ float w[K * C];
    for (int i = threadIdx.x; i < K * C; i += 256) w[i] = W[i];
    __syncthreads();
    constexpr int CG = C / 4;        // col groups of 4
    constexpr int RIF = 256 / CG;    // rows in flight per block iter
    const int colg = threadIdx.x % CG;
    const int rloc = threadIdx.x / CG;
    const float4* w4 = (const float4*)w;
    const float4 bv = ((const float4*)bias)[colg];
    for (int row0 = blockIdx.x * RIF; row0 < n; row0 += gridDim.x * RIF) {
        int row = row0 + rloc;
        if (row >= n) continue;
        float4 acc = bv;
        const float4* in4 = (const float4*)(in + (size_t)row * K);
#pragma unroll 8
        for (int kk = 0; kk < K / 4; ++kk) {
            float4 a = in4[kk];
            const float* ap = &a.x;
#pragma unroll
            for (int j = 0; j < 4; ++j) {
                float4 wv = w4[(kk * 4 + j) * CG + colg];
                acc.x = fmaf(ap[j], wv.x, acc.x);
                acc.y = fmaf(ap[j], wv.y, acc.y);
                acc.z = fmaf(ap[j], wv.z, acc.z);
                acc.w = fmaf(ap[j], wv.w, acc.w);
            }
        }
        if (RELU) {
            acc.x = fmaxf(acc.x, 0.f); acc.y = fmaxf(acc.y, 0.f);
            acc.z = fmaxf(acc.z, 0.f); acc.w = fmaxf(acc.w, 0.f);
        }
        ((float4*)(out + (size_t)row * C))[colg] = acc;
    }
}

// Four linears sharing one input (q,k,v,skip projections), W's staged in LDS one by one.
template <int K, int C>
__global__ __launch_bounds__(256) void proj4_kernel(
    const float* __restrict__ in, int n,
    const float* __restrict__ Wa, const float* __restrict__ ba, float* __restrict__ oa,
    const float* __restrict__ Wb, const float* __restrict__ bb, float* __restrict__ ob,
    const float* __restrict__ Wc, const float* __restrict__ bc, float* __restrict__ oc,
    const float* __restrict__ Wd, const float* __restrict__ bd, float* __restrict__ od) {
    __shared__ float w[K * C];
    const float* Ws[4] = {Wa, Wb, Wc, Wd};
    const float* Bs[4] = {ba, bb, bc, bd};
    float* Os[4] = {oa, ob, oc, od};
    constexpr int CG = C / 4;
    constexpr int RIF = 256 / CG;
    const int colg = threadIdx.x % CG;
    const int rloc = threadIdx.x / CG;
#pragma unroll
    for (int j = 0; j < 4; ++j) {
        __syncthreads();
        for (int i = threadIdx.x; i < K * C; i += 256) w[i] = Ws[j][i];
        __syncthreads();
        const float4* w4 = (const float4*)w;
        const float4 bv = ((const float4*)Bs[j])[colg];
        float* out = Os[j];
        for (int row0 = blockIdx.x * RIF; row0 < n; row0 += gridDim.x * RIF) {
            int row = row0 + rloc;
            if (row >= n) continue;
            float4 acc = bv;
            const float4* in4 = (const float4*)(in + (size_t)row * K);
#pragma unroll 8
            for (int kk = 0; kk < K / 4; ++kk) {
                float4 a = in4[kk];
                const float* ap = &a.x;
#pragma unroll
                for (int jj = 0; jj < 4; ++jj) {
                    float4 wv = w4[(kk * 4 + jj) * CG + colg];
                    acc.x = fmaf(ap[jj], wv.x, acc.x);
                    acc.y = fmaf(ap[jj], wv.y, acc.y);
                    acc.z = fmaf(ap[jj], wv.z, acc.z);
                    acc.w = fmaf(ap[jj], wv.w, acc.w);
                }
            }
            ((float4*)(out + (size_t)row * C))[colg] = acc;
        }
    }
}

// ---------------------------------------------------------------------------
// TransformerConv aggregation: one wave per (dst node, head).
// Online softmax over incoming edges, fused skip-add (+ optional ReLU).
// c = 64 per head, lane = channel.
// ---------------------------------------------------------------------------
__device__ __forceinline__ float wave_reduce_sum(float v) {
#pragma unroll
    for (int off = 32; off > 0; off >>= 1) v += __shfl_xor(v, off, 64);
    return v;
}

template <int HEADS, bool RELU>
__global__ __launch_bounds__(256) void attn_kernel(
    const float* __restrict__ q, const float* __restrict__ k,
    const float* __restrict__ v, const float* __restrict__ s,
    const int* __restrict__ offs, const int* __restrict__ csrc,
    float* __restrict__ out, int n) {
    const int wv = threadIdx.x >> 6;
    const int lane = threadIdx.x & 63;
    constexpr int C = HEADS * 64;
    int node, head;
    if (HEADS == 4) { node = blockIdx.x; head = wv; }
    else            { node = blockIdx.x * 4 + wv; head = 0; }
    if (node >= n) return;
    const int col = head * 64 + lane;
    const float qv = q[(size_t)node * C + col] * 0.125f;  // 1/sqrt(64)
    const int e0 = offs[node], e1 = offs[node + 1];
    float m = -INFINITY, denom = 0.f, acc = 0.f;
    for (int e = e0; e < e1; ++e) {
        const int src = csrc[e];
        float dot = qv * k[(size_t)src * C + col];
        dot = wave_reduce_sum(dot);           // alpha (already scaled)
        float mnew = fmaxf(m, dot);
        float f = __expf(m - mnew);           // exp(-inf)=0 on first edge
        float wgt = __expf(dot - mnew);
        float vv = v[(size_t)src * C + col];
        acc = acc * f + wgt * vv;
        denom = denom * f + wgt;
        m = mnew;
    }
    float o = acc / (denom + 1e-16f) + s[(size_t)node * C + col];
    if (RELU) o = fmaxf(o, 0.f);
    out[(size_t)node * C + col] = o;
}

// ---------------------------------------------------------------------------
extern "C" void kernel_launch(void* const* d_in, const int* in_sizes, int n_in,
                              void* d_out, int out_size, void* d_ws, size_t ws_size,
                              hipStream_t stream) {
    const float* x   = (const float*)d_in[0];
    const int*   ei  = (const int*)d_in[1];
    const float* W1  = (const float*)d_in[2];
    const float* b1  = (const float*)d_in[3];
    const float* Wq1 = (const float*)d_in[4];  const float* bq1 = (const float*)d_in[5];
    const float* Wk1 = (const float*)d_in[6];  const float* bk1 = (const float*)d_in[7];
    const float* Wv1 = (const float*)d_in[8];  const float* bv1 = (const float*)d_in[9];
    const float* Ws1 = (const float*)d_in[10]; const float* bs1 = (const float*)d_in[11];
    const float* Wq2 = (const float*)d_in[12]; const float* bq2 = (const float*)d_in[13];
    const float* Wk2 = (const float*)d_in[14]; const float* bk2 = (const float*)d_in[15];
    const float* Wv2 = (const float*)d_in[16]; const float* bv2 = (const float*)d_in[17];
    const float* Ws2 = (const float*)d_in[18]; const float* bs2 = (const float*)d_in[19];

    const int N = in_sizes[0] / 128;
    const int E = in_sizes[1] / 2;
    const int* srcv = ei;
    const int* dstv = ei + E;

    // workspace carve (256B aligned)
    char* p = (char*)d_ws;
    auto alloc = [&](size_t bytes) -> void* {
        void* r = (void*)p;
        p += (bytes + 255) & ~(size_t)255;
        return r;
    };
    float* h1 = (float*)alloc((size_t)N * 64 * 4);
    float* q1 = (float*)alloc((size_t)N * 256 * 4);
    float* k1 = (float*)alloc((size_t)N * 256 * 4);
    float* v1 = (float*)alloc((size_t)N * 256 * 4);
    float* s1 = (float*)alloc((size_t)N * 256 * 4);
    float* h2 = (float*)alloc((size_t)N * 256 * 4);
    float* q2 = (float*)alloc((size_t)N * 64 * 4);
    float* k2 = (float*)alloc((size_t)N * 64 * 4);
    float* v2 = (float*)alloc((size_t)N * 64 * 4);
    float* s2 = (float*)alloc((size_t)N * 64 * 4);
    int* deg    = (int*)alloc((size_t)N * 4);
    int* offs   = (int*)alloc(((size_t)N + 1) * 4);
    int* cursor = (int*)alloc((size_t)N * 4);
    int* csrc   = (int*)alloc((size_t)E * 4);
    (void)ws_size; (void)n_in; (void)out_size;

    // --- CSR build (shared by both convs) ---
    hipMemsetAsync(deg, 0, (size_t)N * 4, stream);
    count_kernel<<<(E + 255) / 256, 256, 0, stream>>>(dstv, deg, E);
    scan_kernel<<<1, 1024, 0, stream>>>(deg, offs, cursor, N);
    fill_kernel<<<(E + 255) / 256, 256, 0, stream>>>(srcv, dstv, cursor, csrc, E);

    // --- layer 0: h1 = relu(x @ W1 + b1) ---
    lin_kernel<128, 64, true><<<(N + 15) / 16, 256, 0, stream>>>(x, W1, b1, h1, N);

    // --- conv1 projections ---
    proj4_kernel<64, 256><<<1024, 256, 0, stream>>>(h1, N,
        Wq1, bq1, q1,  Wk1, bk1, k1,  Wv1, bv1, v1,  Ws1, bs1, s1);

    // --- conv1 aggregation + skip + relu -> h2 ---
    attn_kernel<4, true><<<N, 256, 0, stream>>>(q1, k1, v1, s1, offs, csrc, h2, N);

    // --- conv2 projections ---
    proj4_kernel<256, 64><<<640, 256, 0, stream>>>(h2, N,
        Wq2, bq2, q2,  Wk2, bk2, k2,  Wv2, bv2, v2,  Ws2, bs2, s2);

    // --- conv2 aggregation + skip -> out ---
    attn_kernel<1, false><<<(N + 3) / 4, 256, 0, stream>>>(q2, k2, v2, s2, offs, csrc,
                                                           (float*)d_out, N);
}

// Round 2
// 344.995 us; speedup vs baseline: 1.1563x; 1.1563x over previous
//
#include <hip/hip_runtime.h>
#include <hip/hip_bf16.h>
#include <math.h>

// ---------------------------------------------------------------------------
// CSR build: count degrees -> single-block scan -> scatter fill (bucketed by dst)
// ---------------------------------------------------------------------------
__global__ void count_kernel(const int* __restrict__ dst, int* __restrict__ deg, int E) {
    int e = blockIdx.x * blockDim.x + threadIdx.x;
    if (e < E) atomicAdd(&deg[dst[e]], 1);
}

__global__ __launch_bounds__(1024) void scan_kernel(const int* __restrict__ deg,
                                                    int* __restrict__ offs,
                                                    int* __restrict__ cursor, int n) {
    __shared__ int sums[1024];
    const int t = threadIdx.x;
    const int CH = (n + 1023) / 1024;
    int lo = t * CH;
    int hi = lo + CH; if (hi > n) hi = n;
    int s = 0;
    for (int i = lo; i < hi; ++i) s += deg[i];
    sums[t] = s;
    __syncthreads();
    for (int off = 1; off < 1024; off <<= 1) {
        int val = (t >= off) ? sums[t - off] : 0;
        __syncthreads();
        sums[t] += val;
        __syncthreads();
    }
    int base = (t == 0) ? 0 : sums[t - 1];
    for (int i = lo; i < hi; ++i) {
        offs[i] = base;
        cursor[i] = base;
        base += deg[i];
    }
    if (t == 1023) offs[n] = sums[1023];
}

__global__ void fill_kernel(const int* __restrict__ src, const int* __restrict__ dst,
                            int* __restrict__ cursor, int* __restrict__ csrc, int E) {
    int e = blockIdx.x * blockDim.x + threadIdx.x;
    if (e < E) {
        int p = atomicAdd(&cursor[dst[e]], 1);
        csrc[p] = src[e];
    }
}

// ---------------------------------------------------------------------------
// Linear: out[n,C] = relu?(in[n,K] @ W[K,C] + b). W staged in LDS.
// ---------------------------------------------------------------------------
template <int K, int C, bool RELU>
__global__ __launch_bounds__(256) void lin_kernel(const float* __restrict__ in,
                                                  const float* __restrict__ W,
                                                  const float* __restrict__ bias,
                                                  float* __restrict__ out, int n) {
    __shared__ float w[K * C];
    for (int i = threadIdx.x; i < K * C; i += 256) w[i] = W[i];
    __syncthreads();
    constexpr int CG = C / 4;
    constexpr int RIF = 256 / CG;
    const int colg = threadIdx.x % CG;
    const int rloc = threadIdx.x / CG;
    const float4* w4 = (const float4*)w;
    const float4 bv = ((const float4*)bias)[colg];
    for (int row0 = blockIdx.x * RIF; row0 < n; row0 += gridDim.x * RIF) {
        int row = row0 + rloc;
        if (row >= n) continue;
        float4 acc = bv;
        const float4* in4 = (const float4*)(in + (size_t)row * K);
#pragma unroll 8
        for (int kk = 0; kk < K / 4; ++kk) {
            float4 a = in4[kk];
            const float* ap = &a.x;
#pragma unroll
            for (int j = 0; j < 4; ++j) {
                float4 wv = w4[(kk * 4 + j) * CG + colg];
                acc.x = fmaf(ap[j], wv.x, acc.x);
                acc.y = fmaf(ap[j], wv.y, acc.y);
                acc.z = fmaf(ap[j], wv.z, acc.z);
                acc.w = fmaf(ap[j], wv.w, acc.w);
            }
        }
        if (RELU) {
            acc.x = fmaxf(acc.x, 0.f); acc.y = fmaxf(acc.y, 0.f);
            acc.z = fmaxf(acc.z, 0.f); acc.w = fmaxf(acc.w, 0.f);
        }
        ((float4*)(out + (size_t)row * C))[colg] = acc;
    }
}

// ---------------------------------------------------------------------------
// Four linears sharing one input (q,k,v,skip). W staged in LDS one at a time.
// Each thread computes R rows x 4 cols so one ds_read_b128 of W feeds 4R FMAs.
// ---------------------------------------------------------------------------
template <int K, int C, int R>
__global__ __launch_bounds__(256) void proj4_kernel(
    const float* __restrict__ in, int n,
    const float* __restrict__ Wa, const float* __restrict__ ba, float* __restrict__ oa,
    const float* __restrict__ Wb, const float* __restrict__ bb, float* __restrict__ ob,
    const float* __restrict__ Wc, const float* __restrict__ bc, float* __restrict__ oc,
    const float* __restrict__ Wd, const float* __restrict__ bd, float* __restrict__ od) {
    __shared__ float w[K * C];
    const float* Ws[4] = {Wa, Wb, Wc, Wd};
    const float* Bs[4] = {ba, bb, bc, bd};
    float* Os[4] = {oa, ob, oc, od};
    constexpr int CG = C / 4;            // col groups of 4
    constexpr int TR = 256 / CG;         // thread-row slots per block
    constexpr int RPI = TR * R;          // rows per block-iter
    const int colg = threadIdx.x % CG;
    const int rloc = threadIdx.x / CG;
#pragma unroll
    for (int j = 0; j < 4; ++j) {
        __syncthreads();
        for (int i = threadIdx.x; i < K * C; i += 256) w[i] = Ws[j][i];
        __syncthreads();
        const float4* w4 = (const float4*)w;
        const float4 bv = ((const float4*)Bs[j])[colg];
        float* out = Os[j];
        for (int row0 = blockIdx.x * RPI; row0 < n; row0 += gridDim.x * RPI) {
            const int rbase = row0 + rloc * R;
            float4 acc[R];
#pragma unroll
            for (int r = 0; r < R; ++r) acc[r] = bv;
            if (rbase + R <= n) {
#pragma unroll 4
                for (int kk = 0; kk < K / 4; ++kk) {
                    float4 a[R];
#pragma unroll
                    for (int r = 0; r < R; ++r)
                        a[r] = ((const float4*)(in + (size_t)(rbase + r) * K))[kk];
#pragma unroll
                    for (int jj = 0; jj < 4; ++jj) {
                        float4 wv = w4[(kk * 4 + jj) * CG + colg];
#pragma unroll
                        for (int r = 0; r < R; ++r) {
                            const float av = (&a[r].x)[jj];
                            acc[r].x = fmaf(av, wv.x, acc[r].x);
                            acc[r].y = fmaf(av, wv.y, acc[r].y);
                            acc[r].z = fmaf(av, wv.z, acc[r].z);
                            acc[r].w = fmaf(av, wv.w, acc[r].w);
                        }
                    }
                }
#pragma unroll
                for (int r = 0; r < R; ++r)
                    ((float4*)(out + (size_t)(rbase + r) * C))[colg] = acc[r];
            } else {
                for (int kk = 0; kk < K / 4; ++kk) {
                    float4 a[R];
#pragma unroll
                    for (int r = 0; r < R; ++r)
                        if (rbase + r < n)
                            a[r] = ((const float4*)(in + (size_t)(rbase + r) * K))[kk];
#pragma unroll
                    for (int jj = 0; jj < 4; ++jj) {
                        float4 wv = w4[(kk * 4 + jj) * CG + colg];
#pragma unroll
                        for (int r = 0; r < R; ++r) {
                            if (rbase + r < n) {
                                const float av = (&a[r].x)[jj];
                                acc[r].x = fmaf(av, wv.x, acc[r].x);
                                acc[r].y = fmaf(av, wv.y, acc[r].y);
                                acc[r].z = fmaf(av, wv.z, acc[r].z);
                                acc[r].w = fmaf(av, wv.w, acc[r].w);
                            }
                        }
                    }
                }
#pragma unroll
                for (int r = 0; r < R; ++r)
                    if (rbase + r < n)
                        ((float4*)(out + (size_t)(rbase + r) * C))[colg] = acc[r];
            }
        }
    }
}

// ---------------------------------------------------------------------------
// TransformerConv aggregation: one wave per (dst node, head).
// Wave split into 4 groups of 16 lanes; each group owns one edge at a time
// (4 edges in flight), holding all 64 head-channels as float4/lane.
// Online softmax per group, 2-step butterfly merge, fused skip (+ReLU).
// ---------------------------------------------------------------------------
template <int HEADS, bool RELU>
__global__ __launch_bounds__(256) void attn_kernel(
    const float* __restrict__ q, const float* __restrict__ k,
    const float* __restrict__ v, const float* __restrict__ s,
    const int* __restrict__ offs, const int* __restrict__ csrc,
    float* __restrict__ out, int n) {
    const int wv = threadIdx.x >> 6;
    const int lane = threadIdx.x & 63;
    const int g = lane >> 4;     // edge group 0..3
    const int sl = lane & 15;    // sublane: owns channels sl*4 .. sl*4+3
    constexpr int C = HEADS * 64;
    int node, head;
    if (HEADS == 4) { node = blockIdx.x; head = wv; }
    else            { node = blockIdx.x * 4 + wv; head = 0; }
    if (node >= n) return;
    const int colbase = head * 64 + sl * 4;

    float4 qv = *(const float4*)(q + (size_t)node * C + colbase);
    qv.x *= 0.125f; qv.y *= 0.125f; qv.z *= 0.125f; qv.w *= 0.125f;  // 1/sqrt(64)

    const int e0 = offs[node], e1 = offs[node + 1];
    float m = -3.0e38f, denom = 0.f;
    float4 acc = {0.f, 0.f, 0.f, 0.f};

    for (int e = e0 + g; e < e1; e += 4) {
        const int src = csrc[e];
        const float* kr = k + (size_t)src * C + colbase;
        const float* vr = v + (size_t)src * C + colbase;
        const float4 k4 = *(const float4*)kr;
        const float4 v4 = *(const float4*)vr;
        float dot = qv.x * k4.x + qv.y * k4.y + qv.z * k4.z + qv.w * k4.w;
        dot += __shfl_xor(dot, 1, 64);
        dot += __shfl_xor(dot, 2, 64);
        dot += __shfl_xor(dot, 4, 64);
        dot += __shfl_xor(dot, 8, 64);
        const float mnew = fmaxf(m, dot);
        const float f = __expf(m - mnew);
        const float wgt = __expf(dot - mnew);
        acc.x = acc.x * f + wgt * v4.x;
        acc.y = acc.y * f + wgt * v4.y;
        acc.z = acc.z * f + wgt * v4.z;
        acc.w = acc.w * f + wgt * v4.w;
        denom = denom * f + wgt;
        m = mnew;
    }

    // merge the 4 groups (butterfly over lanes 16, 32)
#pragma unroll
    for (int off = 16; off <= 32; off <<= 1) {
        const float m_o = __shfl_xor(m, off, 64);
        const float d_o = __shfl_xor(denom, off, 64);
        float4 a_o;
        a_o.x = __shfl_xor(acc.x, off, 64);
        a_o.y = __shfl_xor(acc.y, off, 64);
        a_o.z = __shfl_xor(acc.z, off, 64);
        a_o.w = __shfl_xor(acc.w, off, 64);
        const float mnew = fmaxf(m, m_o);
        const float fs = __expf(m - mnew);
        const float fo = __expf(m_o - mnew);
        acc.x = acc.x * fs + a_o.x * fo;
        acc.y = acc.y * fs + a_o.y * fo;
        acc.z = acc.z * fs + a_o.z * fo;
        acc.w = acc.w * fs + a_o.w * fo;
        denom = denom * fs + d_o * fo;
        m = mnew;
    }

    if (g == 0) {
        const float4 sv = *(const float4*)(s + (size_t)node * C + colbase);
        const float inv = 1.f / (denom + 1e-16f);
        float4 o;
        o.x = acc.x * inv + sv.x;
        o.y = acc.y * inv + sv.y;
        o.z = acc.z * inv + sv.z;
        o.w = acc.w * inv + sv.w;
        if (RELU) {
            o.x = fmaxf(o.x, 0.f); o.y = fmaxf(o.y, 0.f);
            o.z = fmaxf(o.z, 0.f); o.w = fmaxf(o.w, 0.f);
        }
        *(float4*)(out + (size_t)node * C + colbase) = o;
    }
}

// ---------------------------------------------------------------------------
extern "C" void kernel_launch(void* const* d_in, const int* in_sizes, int n_in,
                              void* d_out, int out_size, void* d_ws, size_t ws_size,
                              hipStream_t stream) {
    const float* x   = (const float*)d_in[0];
    const int*   ei  = (const int*)d_in[1];
    const float* W1  = (const float*)d_in[2];
    const float* b1  = (const float*)d_in[3];
    const float* Wq1 = (const float*)d_in[4];  const float* bq1 = (const float*)d_in[5];
    const float* Wk1 = (const float*)d_in[6];  const float* bk1 = (const float*)d_in[7];
    const float* Wv1 = (const float*)d_in[8];  const float* bv1 = (const float*)d_in[9];
    const float* Ws1 = (const float*)d_in[10]; const float* bs1 = (const float*)d_in[11];
    const float* Wq2 = (const float*)d_in[12]; const float* bq2 = (const float*)d_in[13];
    const float* Wk2 = (const float*)d_in[14]; const float* bk2 = (const float*)d_in[15];
    const float* Wv2 = (const float*)d_in[16]; const float* bv2 = (const float*)d_in[17];
    const float* Ws2 = (const float*)d_in[18]; const float* bs2 = (const float*)d_in[19];

    const int N = in_sizes[0] / 128;
    const int E = in_sizes[1] / 2;
    const int* srcv = ei;
    const int* dstv = ei + E;

    char* p = (char*)d_ws;
    auto alloc = [&](size_t bytes) -> void* {
        void* r = (void*)p;
        p += (bytes + 255) & ~(size_t)255;
        return r;
    };
    float* h1 = (float*)alloc((size_t)N * 64 * 4);
    float* q1 = (float*)alloc((size_t)N * 256 * 4);
    float* k1 = (float*)alloc((size_t)N * 256 * 4);
    float* v1 = (float*)alloc((size_t)N * 256 * 4);
    float* s1 = (float*)alloc((size_t)N * 256 * 4);
    float* h2 = (float*)alloc((size_t)N * 256 * 4);
    float* q2 = (float*)alloc((size_t)N * 64 * 4);
    float* k2 = (float*)alloc((size_t)N * 64 * 4);
    float* v2 = (float*)alloc((size_t)N * 64 * 4);
    float* s2 = (float*)alloc((size_t)N * 64 * 4);
    int* deg    = (int*)alloc((size_t)N * 4);
    int* offs   = (int*)alloc(((size_t)N + 1) * 4);
    int* cursor = (int*)alloc((size_t)N * 4);
    int* csrc   = (int*)alloc((size_t)E * 4);
    (void)ws_size; (void)n_in; (void)out_size;

    // --- CSR build ---
    hipMemsetAsync(deg, 0, (size_t)N * 4, stream);
    count_kernel<<<(E + 255) / 256, 256, 0, stream>>>(dstv, deg, E);
    scan_kernel<<<1, 1024, 0, stream>>>(deg, offs, cursor, N);
    fill_kernel<<<(E + 255) / 256, 256, 0, stream>>>(srcv, dstv, cursor, csrc, E);

    // --- layer 0: h1 = relu(x @ W1 + b1) ---
    lin_kernel<128, 64, true><<<(N + 15) / 16, 256, 0, stream>>>(x, W1, b1, h1, N);

    // --- conv1 projections (R=4: 16 rows/block-iter, grid 625 -> 2 iters) ---
    proj4_kernel<64, 256, 4><<<625, 256, 0, stream>>>(h1, N,
        Wq1, bq1, q1,  Wk1, bk1, k1,  Wv1, bv1, v1,  Ws1, bs1, s1);

    // --- conv1 aggregation + skip + relu -> h2 ---
    attn_kernel<4, true><<<N, 256, 0, stream>>>(q1, k1, v1, s1, offs, csrc, h2, N);

    // --- conv2 projections (R=2: 32 rows/block-iter, grid 625 -> 1 iter) ---
    proj4_kernel<256, 64, 2><<<625, 256, 0, stream>>>(h2, N,
        Wq2, bq2, q2,  Wk2, bk2, k2,  Wv2, bv2, v2,  Ws2, bs2, s2);

    // --- conv2 aggregation + skip -> out ---
    attn_kernel<1, false><<<(N + 3) / 4, 256, 0, stream>>>(q2, k2, v2, s2, offs, csrc,
                                                           (float*)d_out, N);
}

// Round 3
// 342.537 us; speedup vs baseline: 1.1646x; 1.0072x over previous
//
#include <hip/hip_runtime.h>
#include <hip/hip_bf16.h>
#include <math.h>

// ---------------------------------------------------------------------------
// CSR build: count degrees -> single-block scan -> scatter fill (bucketed by dst)
// ---------------------------------------------------------------------------
__global__ void count_kernel(const int* __restrict__ dst, int* __restrict__ deg, int E) {
    int e = blockIdx.x * blockDim.x + threadIdx.x;
    if (e < E) atomicAdd(&deg[dst[e]], 1);
}

__global__ __launch_bounds__(1024) void scan_kernel(const int* __restrict__ deg,
                                                    int* __restrict__ offs,
                                                    int* __restrict__ cursor, int n) {
    __shared__ int sums[1024];
    const int t = threadIdx.x;
    const int CH = (n + 1023) / 1024;
    int lo = t * CH;
    int hi = lo + CH; if (hi > n) hi = n;
    int s = 0;
    for (int i = lo; i < hi; ++i) s += deg[i];
    sums[t] = s;
    __syncthreads();
    for (int off = 1; off < 1024; off <<= 1) {
        int val = (t >= off) ? sums[t - off] : 0;
        __syncthreads();
        sums[t] += val;
        __syncthreads();
    }
    int base = (t == 0) ? 0 : sums[t - 1];
    for (int i = lo; i < hi; ++i) {
        offs[i] = base;
        cursor[i] = base;
        base += deg[i];
    }
    if (t == 1023) offs[n] = sums[1023];
}

__global__ void fill_kernel(const int* __restrict__ src, const int* __restrict__ dst,
                            int* __restrict__ cursor, int* __restrict__ csrc, int E) {
    int e = blockIdx.x * blockDim.x + threadIdx.x;
    if (e < E) {
        int p = atomicAdd(&cursor[dst[e]], 1);
        csrc[p] = src[e];
    }
}

// ---------------------------------------------------------------------------
// Linear: out[n,C] = relu?(in[n,K] @ W[K,C] + b). W staged in LDS.
// ---------------------------------------------------------------------------
template <int K, int C, bool RELU>
__global__ __launch_bounds__(256) void lin_kernel(const float* __restrict__ in,
                                                  const float* __restrict__ W,
                                                  const float* __restrict__ bias,
                                                  float* __restrict__ out, int n) {
    __shared__ float w[K * C];
    for (int i = threadIdx.x; i < K * C; i += 256) w[i] = W[i];
    __syncthreads();
    constexpr int CG = C / 4;
    constexpr int RIF = 256 / CG;
    const int colg = threadIdx.x % CG;
    const int rloc = threadIdx.x / CG;
    const float4* w4 = (const float4*)w;
    const float4 bv = ((const float4*)bias)[colg];
    for (int row0 = blockIdx.x * RIF; row0 < n; row0 += gridDim.x * RIF) {
        int row = row0 + rloc;
        if (row >= n) continue;
        float4 acc = bv;
        const float4* in4 = (const float4*)(in + (size_t)row * K);
#pragma unroll 8
        for (int kk = 0; kk < K / 4; ++kk) {
            float4 a = in4[kk];
            const float* ap = &a.x;
#pragma unroll
            for (int j = 0; j < 4; ++j) {
                float4 wv = w4[(kk * 4 + j) * CG + colg];
                acc.x = fmaf(ap[j], wv.x, acc.x);
                acc.y = fmaf(ap[j], wv.y, acc.y);
                acc.z = fmaf(ap[j], wv.z, acc.z);
                acc.w = fmaf(ap[j], wv.w, acc.w);
            }
        }
        if (RELU) {
            acc.x = fmaxf(acc.x, 0.f); acc.y = fmaxf(acc.y, 0.f);
            acc.z = fmaxf(acc.z, 0.f); acc.w = fmaxf(acc.w, 0.f);
        }
        ((float4*)(out + (size_t)row * C))[colg] = acc;
    }
}

// ---------------------------------------------------------------------------
// Four linears sharing one input (q,k,v,skip). W staged in LDS one at a time.
// ---------------------------------------------------------------------------
template <int K, int C, int R>
__global__ __launch_bounds__(256) void proj4_kernel(
    const float* __restrict__ in, int n,
    const float* __restrict__ Wa, const float* __restrict__ ba, float* __restrict__ oa,
    const float* __restrict__ Wb, const float* __restrict__ bb, float* __restrict__ ob,
    const float* __restrict__ Wc, const float* __restrict__ bc, float* __restrict__ oc,
    const float* __restrict__ Wd, const float* __restrict__ bd, float* __restrict__ od) {
    __shared__ float w[K * C];
    const float* Ws[4] = {Wa, Wb, Wc, Wd};
    const float* Bs[4] = {ba, bb, bc, bd};
    float* Os[4] = {oa, ob, oc, od};
    constexpr int CG = C / 4;
    constexpr int TR = 256 / CG;
    constexpr int RPI = TR * R;
    const int colg = threadIdx.x % CG;
    const int rloc = threadIdx.x / CG;
#pragma unroll
    for (int j = 0; j < 4; ++j) {
        __syncthreads();
        for (int i = threadIdx.x; i < K * C; i += 256) w[i] = Ws[j][i];
        __syncthreads();
        const float4* w4 = (const float4*)w;
        const float4 bv = ((const float4*)Bs[j])[colg];
        float* out = Os[j];
        for (int row0 = blockIdx.x * RPI; row0 < n; row0 += gridDim.x * RPI) {
            const int rbase = row0 + rloc * R;
            float4 acc[R];
#pragma unroll
            for (int r = 0; r < R; ++r) acc[r] = bv;
            if (rbase + R <= n) {
#pragma unroll 4
                for (int kk = 0; kk < K / 4; ++kk) {
                    float4 a[R];
#pragma unroll
                    for (int r = 0; r < R; ++r)
                        a[r] = ((const float4*)(in + (size_t)(rbase + r) * K))[kk];
#pragma unroll
                    for (int jj = 0; jj < 4; ++jj) {
                        float4 wv = w4[(kk * 4 + jj) * CG + colg];
#pragma unroll
                        for (int r = 0; r < R; ++r) {
                            const float av = (&a[r].x)[jj];
                            acc[r].x = fmaf(av, wv.x, acc[r].x);
                            acc[r].y = fmaf(av, wv.y, acc[r].y);
                            acc[r].z = fmaf(av, wv.z, acc[r].z);
                            acc[r].w = fmaf(av, wv.w, acc[r].w);
                        }
                    }
                }
#pragma unroll
                for (int r = 0; r < R; ++r)
                    ((float4*)(out + (size_t)(rbase + r) * C))[colg] = acc[r];
            } else {
                for (int kk = 0; kk < K / 4; ++kk) {
                    float4 a[R];
#pragma unroll
                    for (int r = 0; r < R; ++r)
                        if (rbase + r < n)
                            a[r] = ((const float4*)(in + (size_t)(rbase + r) * K))[kk];
#pragma unroll
                    for (int jj = 0; jj < 4; ++jj) {
                        float4 wv = w4[(kk * 4 + jj) * CG + colg];
#pragma unroll
                        for (int r = 0; r < R; ++r) {
                            if (rbase + r < n) {
                                const float av = (&a[r].x)[jj];
                                acc[r].x = fmaf(av, wv.x, acc[r].x);
                                acc[r].y = fmaf(av, wv.y, acc[r].y);
                                acc[r].z = fmaf(av, wv.z, acc[r].z);
                                acc[r].w = fmaf(av, wv.w, acc[r].w);
                            }
                        }
                    }
                }
#pragma unroll
                for (int r = 0; r < R; ++r)
                    if (rbase + r < n)
                        ((float4*)(out + (size_t)(rbase + r) * C))[colg] = acc[r];
            }
        }
    }
}

// ---------------------------------------------------------------------------
// TransformerConv aggregation: one wave per (dst node, head).
// 8 groups of 8 lanes; each group owns one edge (8 edges in flight/wave),
// each lane holds 8 channels (two float4 = 32B, coalesced 256B per group).
// Software-pipelined: src index fetched 2 iters ahead, k/v rows 1 iter ahead.
// Online softmax per group, 3-step butterfly merge, fused skip (+ReLU).
// ---------------------------------------------------------------------------
template <int HEADS, bool RELU>
__global__ __launch_bounds__(256) void attn_kernel(
    const float* __restrict__ q, const float* __restrict__ k,
    const float* __restrict__ v, const float* __restrict__ s,
    const int* __restrict__ offs, const int* __restrict__ csrc,
    float* __restrict__ out, int n) {
    const int wv = threadIdx.x >> 6;
    const int lane = threadIdx.x & 63;
    const int g = lane >> 3;     // edge group 0..7
    const int sl = lane & 7;     // sublane: owns channels sl*8 .. sl*8+7
    constexpr int C = HEADS * 64;
    int node, head;
    if (HEADS == 4) { node = blockIdx.x; head = wv; }
    else            { node = blockIdx.x * 4 + wv; head = 0; }
    if (node >= n) return;
    const int colbase = head * 64 + sl * 8;

    const float* qp = q + (size_t)node * C + colbase;
    float4 qa = *(const float4*)qp;
    float4 qb = *(const float4*)(qp + 4);
    qa.x *= 0.125f; qa.y *= 0.125f; qa.z *= 0.125f; qa.w *= 0.125f;  // 1/sqrt(64)
    qb.x *= 0.125f; qb.y *= 0.125f; qb.z *= 0.125f; qb.w *= 0.125f;

    const int e0 = offs[node], e1 = offs[node + 1];
    float m = -3.0e38f, denom = 0.f;
    float acc[8] = {0.f, 0.f, 0.f, 0.f, 0.f, 0.f, 0.f, 0.f};

    // pipeline prologue: iter0 data + iter1 src index
    int e = e0 + g;
    bool valid = e < e1;
    float4 ka, kb, va, vb;
    if (valid) {
        const int src = csrc[e];
        const float* kr = k + (size_t)src * C + colbase;
        const float* vr = v + (size_t)src * C + colbase;
        ka = *(const float4*)kr; kb = *(const float4*)(kr + 4);
        va = *(const float4*)vr; vb = *(const float4*)(vr + 4);
    }
    int en = e + 8;
    bool vn = en < e1;
    int srcn = vn ? csrc[en] : 0;

    while (valid) {
        // prefetch iter+1 k/v rows (index already resident)
        float4 kan, kbn, van, vbn;
        if (vn) {
            const float* kr = k + (size_t)srcn * C + colbase;
            const float* vr = v + (size_t)srcn * C + colbase;
            kan = *(const float4*)kr; kbn = *(const float4*)(kr + 4);
            van = *(const float4*)vr; vbn = *(const float4*)(vr + 4);
        }
        // prefetch iter+2 src index
        const int en2 = en + 8;
        const bool vn2 = en2 < e1;
        const int srcn2 = vn2 ? csrc[en2] : 0;

        // compute current edge
        float dot = qa.x * ka.x + qa.y * ka.y + qa.z * ka.z + qa.w * ka.w
                  + qb.x * kb.x + qb.y * kb.y + qb.z * kb.z + qb.w * kb.w;
        dot += __shfl_xor(dot, 1, 64);
        dot += __shfl_xor(dot, 2, 64);
        dot += __shfl_xor(dot, 4, 64);
        const float mnew = fmaxf(m, dot);
        const float f = __expf(m - mnew);
        const float wgt = __expf(dot - mnew);
        acc[0] = acc[0] * f + wgt * va.x;
        acc[1] = acc[1] * f + wgt * va.y;
        acc[2] = acc[2] * f + wgt * va.z;
        acc[3] = acc[3] * f + wgt * va.w;
        acc[4] = acc[4] * f + wgt * vb.x;
        acc[5] = acc[5] * f + wgt * vb.y;
        acc[6] = acc[6] * f + wgt * vb.z;
        acc[7] = acc[7] * f + wgt * vb.w;
        denom = denom * f + wgt;
        m = mnew;

        // shift pipeline
        valid = vn; vn = vn2;
        en = en2; srcn = srcn2;
        ka = kan; kb = kbn; va = van; vb = vbn;
    }

    // merge the 8 groups (butterfly over lanes 8, 16, 32)
#pragma unroll
    for (int off = 8; off <= 32; off <<= 1) {
        const float m_o = __shfl_xor(m, off, 64);
        const float d_o = __shfl_xor(denom, off, 64);
        float a_o[8];
#pragma unroll
        for (int i = 0; i < 8; ++i) a_o[i] = __shfl_xor(acc[i], off, 64);
        const float mnew = fmaxf(m, m_o);
        const float fs = __expf(m - mnew);
        const float fo = __expf(m_o - mnew);
#pragma unroll
        for (int i = 0; i < 8; ++i) acc[i] = acc[i] * fs + a_o[i] * fo;
        denom = denom * fs + d_o * fo;
        m = mnew;
    }

    if (g == 0) {
        const float* sp = s + (size_t)node * C + colbase;
        const float4 sva = *(const float4*)sp;
        const float4 svb = *(const float4*)(sp + 4);
        const float inv = 1.f / (denom + 1e-16f);
        float4 oa, ob;
        oa.x = acc[0] * inv + sva.x; oa.y = acc[1] * inv + sva.y;
        oa.z = acc[2] * inv + sva.z; oa.w = acc[3] * inv + sva.w;
        ob.x = acc[4] * inv + svb.x; ob.y = acc[5] * inv + svb.y;
        ob.z = acc[6] * inv + svb.z; ob.w = acc[7] * inv + svb.w;
        if (RELU) {
            oa.x = fmaxf(oa.x, 0.f); oa.y = fmaxf(oa.y, 0.f);
            oa.z = fmaxf(oa.z, 0.f); oa.w = fmaxf(oa.w, 0.f);
            ob.x = fmaxf(ob.x, 0.f); ob.y = fmaxf(ob.y, 0.f);
            ob.z = fmaxf(ob.z, 0.f); ob.w = fmaxf(ob.w, 0.f);
        }
        float* op = out + (size_t)node * C + colbase;
        *(float4*)op = oa;
        *(float4*)(op + 4) = ob;
    }
}

// ---------------------------------------------------------------------------
extern "C" void kernel_launch(void* const* d_in, const int* in_sizes, int n_in,
                              void* d_out, int out_size, void* d_ws, size_t ws_size,
                              hipStream_t stream) {
    const float* x   = (const float*)d_in[0];
    const int*   ei  = (const int*)d_in[1];
    const float* W1  = (const float*)d_in[2];
    const float* b1  = (const float*)d_in[3];
    const float* Wq1 = (const float*)d_in[4];  const float* bq1 = (const float*)d_in[5];
    const float* Wk1 = (const float*)d_in[6];  const float* bk1 = (const float*)d_in[7];
    const float* Wv1 = (const float*)d_in[8];  const float* bv1 = (const float*)d_in[9];
    const float* Ws1 = (const float*)d_in[10]; const float* bs1 = (const float*)d_in[11];
    const float* Wq2 = (const float*)d_in[12]; const float* bq2 = (const float*)d_in[13];
    const float* Wk2 = (const float*)d_in[14]; const float* bk2 = (const float*)d_in[15];
    const float* Wv2 = (const float*)d_in[16]; const float* bv2 = (const float*)d_in[17];
    const float* Ws2 = (const float*)d_in[18]; const float* bs2 = (const float*)d_in[19];

    const int N = in_sizes[0] / 128;
    const int E = in_sizes[1] / 2;
    const int* srcv = ei;
    const int* dstv = ei + E;

    char* p = (char*)d_ws;
    auto alloc = [&](size_t bytes) -> void* {
        void* r = (void*)p;
        p += (bytes + 255) & ~(size_t)255;
        return r;
    };
    float* h1 = (float*)alloc((size_t)N * 64 * 4);
    float* q1 = (float*)alloc((size_t)N * 256 * 4);
    float* k1 = (float*)alloc((size_t)N * 256 * 4);
    float* v1 = (float*)alloc((size_t)N * 256 * 4);
    float* s1 = (float*)alloc((size_t)N * 256 * 4);
    float* h2 = (float*)alloc((size_t)N * 256 * 4);
    float* q2 = (float*)alloc((size_t)N * 64 * 4);
    float* k2 = (float*)alloc((size_t)N * 64 * 4);
    float* v2 = (float*)alloc((size_t)N * 64 * 4);
    float* s2 = (float*)alloc((size_t)N * 64 * 4);
    int* deg    = (int*)alloc((size_t)N * 4);
    int* offs   = (int*)alloc(((size_t)N + 1) * 4);
    int* cursor = (int*)alloc((size_t)N * 4);
    int* csrc   = (int*)alloc((size_t)E * 4);
    (void)ws_size; (void)n_in; (void)out_size;

    // --- CSR build ---
    hipMemsetAsync(deg, 0, (size_t)N * 4, stream);
    count_kernel<<<(E + 255) / 256, 256, 0, stream>>>(dstv, deg, E);
    scan_kernel<<<1, 1024, 0, stream>>>(deg, offs, cursor, N);
    fill_kernel<<<(E + 255) / 256, 256, 0, stream>>>(srcv, dstv, cursor, csrc, E);

    // --- layer 0: h1 = relu(x @ W1 + b1) ---
    lin_kernel<128, 64, true><<<(N + 15) / 16, 256, 0, stream>>>(x, W1, b1, h1, N);

    // --- conv1 projections ---
    proj4_kernel<64, 256, 4><<<625, 256, 0, stream>>>(h1, N,
        Wq1, bq1, q1,  Wk1, bk1, k1,  Wv1, bv1, v1,  Ws1, bs1, s1);

    // --- conv1 aggregation + skip + relu -> h2 ---
    attn_kernel<4, true><<<N, 256, 0, stream>>>(q1, k1, v1, s1, offs, csrc, h2, N);

    // --- conv2 projections ---
    proj4_kernel<256, 64, 2><<<625, 256, 0, stream>>>(h2, N,
        Wq2, bq2, q2,  Wk2, bk2, k2,  Wv2, bv2, v2,  Ws2, bs2, s2);

    // --- conv2 aggregation + skip -> out ---
    attn_kernel<1, false><<<(N + 3) / 4, 256, 0, stream>>>(q2, k2, v2, s2, offs, csrc,
                                                           (float*)d_out, N);
}